// Round 1
// baseline (61.197 us; speedup 1.0000x reference)
//
#include <hip/hip_runtime.h>

#define BS 2048
#define DIM 256
#define MARGIN_F 0.3f
#define TILE 64
#define KC 64

// Kernel 1: per-row norms. sn[j]=||sketch_j||^2, pn[i]=||photo_i||^2,
// pos[j]=||sketch_j - photo_j||. One block (256 threads) per row, one
// element per thread (DIM==256).
__global__ __launch_bounds__(256) void tl_norms(const float* __restrict__ sketch,
                                                const float* __restrict__ photo,
                                                float* __restrict__ sn,
                                                float* __restrict__ pn,
                                                float* __restrict__ pos) {
    const int row = blockIdx.x;
    const int t = threadIdx.x;
    float s = sketch[(size_t)row * DIM + t];
    float p = photo[(size_t)row * DIM + t];
    float d = s - p;
    float vs = s * s, vp = p * p, vd = d * d;
    #pragma unroll
    for (int off = 32; off > 0; off >>= 1) {
        vs += __shfl_down(vs, off);
        vp += __shfl_down(vp, off);
        vd += __shfl_down(vd, off);
    }
    __shared__ float ls[4], lp[4], ldd[4];
    const int wave = t >> 6, lane = t & 63;
    if (lane == 0) { ls[wave] = vs; lp[wave] = vp; ldd[wave] = vd; }
    __syncthreads();
    if (t == 0) {
        sn[row]  = ls[0] + ls[1] + ls[2] + ls[3];
        pn[row]  = lp[0] + lp[1] + lp[2] + lp[3];
        pos[row] = sqrtf(ldd[0] + ldd[1] + ldd[2] + ldd[3]);
    }
}

// Kernel 2: fused cross-GEMM + triplet epilogue + global mean.
// 64x64 output tile per 256-thread block; each thread owns a 4x4 micro-tile.
// i (rows) index photo, j (cols) index sketch.
__global__ __launch_bounds__(256) void tl_main(const float* __restrict__ sketch,
                                               const float* __restrict__ photo,
                                               const float* __restrict__ sn,
                                               const float* __restrict__ pn,
                                               const float* __restrict__ pos,
                                               float* __restrict__ out) {
    __shared__ float la[TILE][KC + 1];  // photo rows   (i), +1 pad: 2-way max
    __shared__ float lb[TILE][KC + 1];  // sketch rows  (j)
    const int i0 = blockIdx.y * TILE;
    const int j0 = blockIdx.x * TILE;
    const int t = threadIdx.x;
    const int tx = t & 15;   // micro-tile i index (0..15)
    const int ty = t >> 4;   // micro-tile j index (0..15)

    float acc[4][4] = {};

    const int lr = t >> 4;         // loader row 0..15 (stride 16)
    const int lc = (t & 15) * 4;   // loader col (float4)

    for (int k0 = 0; k0 < DIM; k0 += KC) {
        #pragma unroll
        for (int rr = lr; rr < TILE; rr += 16) {
            float4 va = *reinterpret_cast<const float4*>(&photo[(size_t)(i0 + rr) * DIM + k0 + lc]);
            float4 vb = *reinterpret_cast<const float4*>(&sketch[(size_t)(j0 + rr) * DIM + k0 + lc]);
            la[rr][lc + 0] = va.x; la[rr][lc + 1] = va.y;
            la[rr][lc + 2] = va.z; la[rr][lc + 3] = va.w;
            lb[rr][lc + 0] = vb.x; lb[rr][lc + 1] = vb.y;
            lb[rr][lc + 2] = vb.z; lb[rr][lc + 3] = vb.w;
        }
        __syncthreads();
        #pragma unroll
        for (int kk = 0; kk < KC; ++kk) {
            float a[4], b[4];
            #pragma unroll
            for (int u = 0; u < 4; ++u) a[u] = la[tx * 4 + u][kk];
            #pragma unroll
            for (int v = 0; v < 4; ++v) b[v] = lb[ty * 4 + v][kk];
            #pragma unroll
            for (int u = 0; u < 4; ++u)
                #pragma unroll
                for (int v = 0; v < 4; ++v)
                    acc[u][v] += a[u] * b[v];
        }
        __syncthreads();
    }

    // Fused epilogue: tl = relu(pos[j] - sqrt(max(pn[i]+sn[j]-2*cross,0)) + m)
    float partial = 0.0f;
    #pragma unroll
    for (int u = 0; u < 4; ++u) {
        const int i = i0 + tx * 4 + u;
        const float pni = pn[i];
        #pragma unroll
        for (int v = 0; v < 4; ++v) {
            const int j = j0 + ty * 4 + v;
            if (i != j) {
                float neg2 = fmaxf(pni + sn[j] - 2.0f * acc[u][v], 0.0f);
                float tl = pos[j] - sqrtf(neg2) + MARGIN_F;
                partial += fmaxf(tl, 0.0f);
            }
        }
    }

    // Block reduction -> one scaled atomicAdd per block.
    #pragma unroll
    for (int off = 32; off > 0; off >>= 1) partial += __shfl_down(partial, off);
    __shared__ float lsum[4];
    const int wave = t >> 6, lane = t & 63;
    if (lane == 0) lsum[wave] = partial;
    __syncthreads();
    if (t == 0) {
        float s = lsum[0] + lsum[1] + lsum[2] + lsum[3];
        atomicAdd(out, s * (1.0f / ((float)BS * (float)BS)));
    }
}

extern "C" void kernel_launch(void* const* d_in, const int* in_sizes, int n_in,
                              void* d_out, int out_size, void* d_ws, size_t ws_size,
                              hipStream_t stream) {
    const float* sketch = (const float*)d_in[0];
    const float* photo  = (const float*)d_in[1];
    float* out = (float*)d_out;

    float* sn  = (float*)d_ws;        // BS floats
    float* pn  = sn + BS;             // BS floats
    float* pos = pn + BS;             // BS floats

    // Harness poisons d_out once and never re-poisons between replays;
    // we accumulate with atomics, so zero it every call.
    hipMemsetAsync(d_out, 0, sizeof(float), stream);

    tl_norms<<<dim3(BS), dim3(DIM), 0, stream>>>(sketch, photo, sn, pn, pos);

    dim3 grid(BS / TILE, BS / TILE);
    tl_main<<<grid, dim3(256), 0, stream>>>(sketch, photo, sn, pn, pos, out);
}

// Round 2
// 27.003 us; speedup vs baseline: 2.2664x; 2.2664x over previous
//
#include <hip/hip_runtime.h>

#define BS 2048
#define DIM 256
#define MARGIN_F 0.3f
#define BM 128
#define BK 64
#define PAD 8   // halves; row stride 72 halves = 144 B -> balanced bank-quad classes

typedef __attribute__((ext_vector_type(4))) float f32x4;
typedef __attribute__((ext_vector_type(8))) _Float16 f16x8;  // 8 halves = 4 VGPRs

// Kernel 1: per-row norms (exact fp32). sn[j]=||sketch_j||^2, pn[i]=||photo_i||^2,
// pos[j]=||sketch_j - photo_j||. One block (256 threads) per row.
__global__ __launch_bounds__(256) void tl_norms(const float* __restrict__ sketch,
                                                const float* __restrict__ photo,
                                                float* __restrict__ sn,
                                                float* __restrict__ pn,
                                                float* __restrict__ pos) {
    const int row = blockIdx.x;
    const int t = threadIdx.x;
    float s = sketch[(size_t)row * DIM + t];
    float p = photo[(size_t)row * DIM + t];
    float d = s - p;
    float vs = s * s, vp = p * p, vd = d * d;
    #pragma unroll
    for (int off = 32; off > 0; off >>= 1) {
        vs += __shfl_down(vs, off);
        vp += __shfl_down(vp, off);
        vd += __shfl_down(vd, off);
    }
    __shared__ float ls[4], lp[4], ldd[4];
    const int wave = t >> 6, lane = t & 63;
    if (lane == 0) { ls[wave] = vs; lp[wave] = vp; ldd[wave] = vd; }
    __syncthreads();
    if (t == 0) {
        sn[row]  = ls[0] + ls[1] + ls[2] + ls[3];
        pn[row]  = lp[0] + lp[1] + lp[2] + lp[3];
        pos[row] = sqrtf(ldd[0] + ldd[1] + ldd[2] + ldd[3]);
    }
}

// Kernel 2: MFMA cross-GEMM (fp16 in, fp32 acc) + fused triplet epilogue + mean.
// 128x128 tile / block, 4 waves, each wave 64x64 = 4x4 fragments of 16x16x32.
// cross[i][j] = photo_i . sketch_j  (A = photo rows, B^T = sketch rows; the
// B-fragment of sketch^T loads with the SAME pattern as an A-fragment).
__global__ __launch_bounds__(256) void tl_mfma(const float* __restrict__ photo,
                                               const float* __restrict__ sketch,
                                               const float* __restrict__ sn,
                                               const float* __restrict__ pn,
                                               const float* __restrict__ pos,
                                               float* __restrict__ out) {
    __shared__ _Float16 As[BM][BK + PAD];  // photo rows (i)
    __shared__ _Float16 Bs[BM][BK + PAD];  // sketch rows (j)

    const int t = threadIdx.x;
    const int i0 = blockIdx.y * BM;
    const int j0 = blockIdx.x * BM;
    const int w = t >> 6, lane = t & 63;
    const int wr = (w >> 1) * 64;   // wave row offset in tile
    const int wc = (w & 1) * 64;    // wave col offset in tile

    f32x4 acc[4][4] = {};

    // Staging: 1024 chunks of 8 halves per operand per K-iter; 4 chunks/thread.
    for (int k0 = 0; k0 < DIM; k0 += BK) {
        #pragma unroll
        for (int q = 0; q < 4; ++q) {
            const int c = t + 256 * q;
            const int r = c >> 3;            // 0..127
            const int col = (c & 7) * 8;     // 0..56
            const float4* pa = reinterpret_cast<const float4*>(&photo[(size_t)(i0 + r) * DIM + k0 + col]);
            const float4* pb = reinterpret_cast<const float4*>(&sketch[(size_t)(j0 + r) * DIM + k0 + col]);
            float4 a0 = pa[0], a1 = pa[1];
            float4 b0 = pb[0], b1 = pb[1];
            f16x8 ha, hb;
            ha[0] = (_Float16)a0.x; ha[1] = (_Float16)a0.y; ha[2] = (_Float16)a0.z; ha[3] = (_Float16)a0.w;
            ha[4] = (_Float16)a1.x; ha[5] = (_Float16)a1.y; ha[6] = (_Float16)a1.z; ha[7] = (_Float16)a1.w;
            hb[0] = (_Float16)b0.x; hb[1] = (_Float16)b0.y; hb[2] = (_Float16)b0.z; hb[3] = (_Float16)b0.w;
            hb[4] = (_Float16)b1.x; hb[5] = (_Float16)b1.y; hb[6] = (_Float16)b1.z; hb[7] = (_Float16)b1.w;
            *reinterpret_cast<f16x8*>(&As[r][col]) = ha;
            *reinterpret_cast<f16x8*>(&Bs[r][col]) = hb;
        }
        __syncthreads();
        #pragma unroll
        for (int ks = 0; ks < BK / 32; ++ks) {
            const int kk = ks * 32 + (lane >> 4) * 8;
            f16x8 af[4], bf[4];
            #pragma unroll
            for (int m = 0; m < 4; ++m)
                af[m] = *reinterpret_cast<const f16x8*>(&As[wr + m * 16 + (lane & 15)][kk]);
            #pragma unroll
            for (int n = 0; n < 4; ++n)
                bf[n] = *reinterpret_cast<const f16x8*>(&Bs[wc + n * 16 + (lane & 15)][kk]);
            #pragma unroll
            for (int m = 0; m < 4; ++m)
                #pragma unroll
                for (int n = 0; n < 4; ++n)
                    acc[m][n] = __builtin_amdgcn_mfma_f32_16x16x32_f16(af[m], bf[n], acc[m][n], 0, 0, 0);
        }
        __syncthreads();
    }

    // Fused epilogue. C/D layout: col = lane&15 (j), row = (lane>>4)*4 + reg (i).
    const int jl = lane & 15;
    const int rl = (lane >> 4) * 4;

    float pnv[16];
    #pragma unroll
    for (int m = 0; m < 4; ++m)
        #pragma unroll
        for (int r = 0; r < 4; ++r)
            pnv[m * 4 + r] = pn[i0 + wr + m * 16 + rl + r];

    float partial = 0.0f;
    #pragma unroll
    for (int n = 0; n < 4; ++n) {
        const int j = j0 + wc + n * 16 + jl;
        const float snj = sn[j];
        const float posj = pos[j];
        #pragma unroll
        for (int m = 0; m < 4; ++m) {
            const int ibase = i0 + wr + m * 16 + rl;
            #pragma unroll
            for (int r = 0; r < 4; ++r) {
                const int i = ibase + r;
                const float c = acc[m][n][r];
                float neg2 = fmaxf(pnv[m * 4 + r] + snj - 2.0f * c, 0.0f);
                float tl = posj - sqrtf(neg2) + MARGIN_F;
                partial += (i != j) ? fmaxf(tl, 0.0f) : 0.0f;
            }
        }
    }

    // Block reduction -> one scaled atomicAdd per block.
    #pragma unroll
    for (int off = 32; off > 0; off >>= 1) partial += __shfl_down(partial, off);
    __shared__ float lsum[4];
    const int wave = t >> 6, lid = t & 63;
    if (lid == 0) lsum[wave] = partial;
    __syncthreads();
    if (t == 0) {
        float s = lsum[0] + lsum[1] + lsum[2] + lsum[3];
        atomicAdd(out, s * (1.0f / ((float)BS * (float)BS)));
    }
}

extern "C" void kernel_launch(void* const* d_in, const int* in_sizes, int n_in,
                              void* d_out, int out_size, void* d_ws, size_t ws_size,
                              hipStream_t stream) {
    const float* sketch = (const float*)d_in[0];
    const float* photo  = (const float*)d_in[1];
    float* out = (float*)d_out;

    float* sn  = (float*)d_ws;        // BS floats
    float* pn  = sn + BS;             // BS floats
    float* pos = pn + BS;             // BS floats

    // We accumulate into d_out with atomics; harness doesn't re-zero between
    // replays, so zero it every call.
    hipMemsetAsync(d_out, 0, sizeof(float), stream);

    tl_norms<<<dim3(BS), dim3(DIM), 0, stream>>>(sketch, photo, sn, pn, pos);

    dim3 grid(BS / BM, BS / BM);   // 16 x 16
    tl_mfma<<<grid, dim3(256), 0, stream>>>(photo, sketch, sn, pn, pos, out);
}